// Round 7
// baseline (599.084 us; speedup 1.0000x reference)
//
#include <hip/hip_runtime.h>
#include <math.h>

#define NA 16384
#define ER 524288
#define EB 32768
#define ET 557056
#define INV_NORM 0.17149858514250882f   // 1/sqrt((ER+EB)/NA) = 1/sqrt(34)
#define SQRT3 1.7320508075688772f
#define RB_STEP (1.5f/9.0f)
#define BINS 512
#define DMAX 2.5f
#define INV_H ((float)BINS / DMAX)
#define TBL_ELEMS (2 * BINS * 256)   // one table: [2][BINS][64][4] floats

typedef float nfloat4 __attribute__((ext_vector_type(4)));

__device__ __forceinline__ float sigmoidf_(float x) { return 1.f / (1.f + __expf(-x)); }

__device__ __forceinline__ int edge_dst(int e, const int* __restrict__ rad, const int* __restrict__ bon) {
  return (e < ER) ? rad[ER + e] : bon[EB + (e - ER)];
}

// ---------------- CSR build ----------------
__global__ void k_zero(int* __restrict__ count) {
  count[blockIdx.x * 256 + threadIdx.x] = 0;
}

__global__ void k_hist(const int* __restrict__ rad, const int* __restrict__ bon, int* __restrict__ count) {
  int e = blockIdx.x * 256 + threadIdx.x;
  atomicAdd(&count[edge_dst(e, rad, bon)], 1);
}

__global__ void k_scan(int* __restrict__ count, int* __restrict__ offsets) {
  __shared__ int part[256];
  int t = threadIdx.x;
  int base = t * 64;
  int s = 0;
  for (int j = 0; j < 64; ++j) s += count[base + j];
  part[t] = s;
  __syncthreads();
  for (int off = 1; off < 256; off <<= 1) {
    int v = (t >= off) ? part[t - off] : 0;
    __syncthreads();
    part[t] += v;
    __syncthreads();
  }
  int run = part[t] - s;  // exclusive prefix
  for (int j = 0; j < 64; ++j) {
    int c = count[base + j];
    offsets[base + j] = run;
    count[base + j] = run;  // becomes cursor for k_fill
    run += c;
  }
  if (t == 255) offsets[NA] = run;
}

__global__ void k_fill(const int* __restrict__ rad, const int* __restrict__ bon,
                       int* __restrict__ cursor, int* __restrict__ sorted) {
  int e = blockIdx.x * 256 + threadIdx.x;
  int d = edge_dst(e, rad, bon);
  int slot = atomicAdd(&cursor[d], 1);
  sorted[slot] = e;
}

// ---------------- per-edge record precompute ----------------
// record[idx] (32B): {src, Y0, Y1, Y2, frac, qoff(elem offset into a table), pad, pad}
__global__ void k_edge_pre(const float* __restrict__ pos,
                           const int* __restrict__ rad, const int* __restrict__ bon,
                           const int* __restrict__ sorted, float* __restrict__ rec8) {
  int idx = blockIdx.x * 256 + threadIdx.x;
  int e = sorted[idx];
  int src, dst, v;
  if (e < ER) { src = rad[e]; dst = rad[ER + e]; v = 0; }
  else        { src = bon[e - ER]; dst = bon[EB + e - ER]; v = 1; }
  float dx = pos[src * 3] - pos[dst * 3];
  float dy = pos[src * 3 + 1] - pos[dst * 3 + 1];
  float dz = pos[src * 3 + 2] - pos[dst * 3 + 2];
  float dist = sqrtf(dx * dx + dy * dy + dz * dz + 1e-12f);
  float inv = 1.f / dist;
  float fq = fminf(dist * INV_H, BINS - 1.001f);
  int q = (int)fq;
  float frac = fq - (float)q;
  int qoff = (v * BINS + q) << 8;   // 256 floats per row
  float* rp = rec8 + (size_t)idx * 8;
  *(float4*)rp = make_float4(__int_as_float(src), SQRT3 * dx * inv, SQRT3 * dy * inv, SQRT3 * dz * inv);
  rp[4] = frac;
  rp[5] = __int_as_float(qoff);
}

// ---------------- radial-weight tables with bond base folded ----------------
// 5 tables, each [variant(2)][BINS][64][4]:
//   t=0: agg0 {w0, dw0, w1, dw1}
//   t=1/3: layer0/1 scalar {w_ss, d, w_sv, d}
//   t=2/4: layer0/1 "U": lane<32 {w_vs, d, w_vv, d}; lane>=32 {w_vx, d, 0, 0}
__global__ void k_build(const float* __restrict__ We0, const float* __restrict__ We1,
                        const float* __restrict__ We_ss, const float* __restrict__ We_vs,
                        const float* __restrict__ We_sv, const float* __restrict__ We_vv,
                        const float* __restrict__ We_vx, const float* __restrict__ bond_tab,
                        float* __restrict__ tabs) {
  int q = blockIdx.x, t = blockIdx.y, v = blockIdx.z, c = threadIdx.x;
  float d0 = q * (DMAX / BINS), d1 = (q + 1) * (DMAX / BINS);
  float rb0[8], rb1[8];
#pragma unroll
  for (int k = 0; k < 8; ++k) {
    float f0 = (d0 - (k + 1) * RB_STEP) * (1.f / RB_STEP);
    float f1 = (d1 - (k + 1) * RB_STEP) * (1.f / RB_STEP);
    rb0[k] = 1.12f * __expf(-f0 * f0);
    rb1[k] = 1.12f * __expf(-f1 * f1);
  }
  const float* A;
  const float* B;
  int stride, coff;
  bool hasB = true;
  if (t == 0) { A = We0; B = We1; stride = 64; coff = c; }
  else if (t == 1 || t == 3) {
    int l = (t == 3);
    A = We_ss + l * 1024; B = We_sv + l * 1024; stride = 64; coff = c;
  } else {
    int l = (t == 4);
    stride = 32; coff = c & 31;
    if (c < 32) { A = We_vs + l * 512; B = We_vv + l * 512; }
    else        { A = We_vx + l * 512; B = nullptr; hasB = false; }
  }
  float ba = 0, bb = 0, a0 = 0, a1 = 0, b0 = 0, b1 = 0;
#pragma unroll
  for (int k = 0; k < 8; ++k) {
    float bt = bond_tab[v * 8 + k];
    float av_lo = A[k * stride + coff], av_hi = A[(8 + k) * stride + coff];
    ba += bt * av_lo;
    a0 += rb0[k] * av_hi; a1 += rb1[k] * av_hi;
    if (hasB) {
      float bv_lo = B[k * stride + coff], bv_hi = B[(8 + k) * stride + coff];
      bb += bt * bv_lo;
      b0 += rb0[k] * bv_hi; b1 += rb1[k] * bv_hi;
    }
  }
  float* o = tabs + (size_t)t * TBL_ELEMS + (((size_t)v * BINS + q) << 8) + c * 4;
  o[0] = ba + a0; o[1] = a1 - a0; o[2] = bb + b0; o[3] = b1 - b0;
}

// ---------------- embedding ----------------
__global__ void k_embed(const float* __restrict__ atom_tab, const int* __restrict__ types,
                        const float* __restrict__ ns0_w, const float* __restrict__ cnoise,
                        float* __restrict__ s_feat) {
  int tid = blockIdx.x * 256 + threadIdx.x;
  int n = tid >> 6, c = tid & 63;
  float cn = cnoise[0];
  s_feat[tid] = atom_tab[types[n] * 64 + c] * (1.f + cn * ns0_w[c]);
}

// ---------------- initial aggregation (wave per node, lane = channel) ----------------
__global__ __launch_bounds__(256, 8) void k_agg0(
    const int* __restrict__ offsets, const float* __restrict__ rec8,
    const float* __restrict__ T0, const float* __restrict__ s_feat,
    float* __restrict__ a_s, float* __restrict__ a_v) {
  int lane = threadIdx.x & 63;
  int n = blockIdx.x * 4 + (threadIdx.x >> 6);
  float acc = 0, a0 = 0, a1 = 0, a2 = 0;
  int beg = __builtin_amdgcn_readfirstlane(offsets[n]);
  int end = __builtin_amdgcn_readfirstlane(offsets[n + 1]);
  if (beg < end) {
    const float* rp = rec8 + (size_t)beg * 8;
    float4 rA = *(const float4*)rp;
    float2 rB = *(const float2*)(rp + 4);
    for (int idx = beg; idx < end; ++idx) {
      int src = __float_as_int(rA.x);
      float frac = rB.x;
      int qoff = __float_as_int(rB.y);
      // gathers for current edge
      float4 t4 = *(const float4*)(T0 + qoff + (lane << 2));
      float sv = s_feat[((size_t)src << 6) + lane];
      // prefetch next record (independent)
      int nidx = (idx + 1 < end) ? idx + 1 : idx;
      const float* np = rec8 + (size_t)nidx * 8;
      float4 nA = *(const float4*)np;
      float2 nB = *(const float2*)(np + 4);
      // compute
      float w0 = fmaf(frac, t4.y, t4.x);
      float w1 = fmaf(frac, t4.w, t4.z);
      acc += w0 * sv;
      float t = w1 * sv;
      a0 += t * rA.y; a1 += t * rA.z; a2 += t * rA.w;
      rA = nA; rB = nB;
    }
  }
  a_s[n * 64 + lane] = acc * INV_NORM;
  float* avp = a_v + (size_t)n * 192 + lane * 3;
  avp[0] = a0 * INV_NORM; avp[1] = a1 * INV_NORM; avp[2] = a2 * INV_NORM;
}

// ---------------- initial projections (merged sh + vh) ----------------
__global__ void k_init(const float* __restrict__ a_s, const float* __restrict__ s_feat,
                       const float* __restrict__ Ws0, const float* __restrict__ Wself0,
                       const float* __restrict__ a_v, const float* __restrict__ Wv0,
                       float* __restrict__ sh, float* __restrict__ vh) {
  int b = blockIdx.x;
  if (b < NA * 64 / 256) {
    int tid = b * 256 + threadIdx.x;
    int n = tid >> 6, d = tid & 63;
    float acc = 0;
    const float* as = a_s + n * 64;
    const float* sp = s_feat + n * 64;
    for (int c = 0; c < 64; ++c)
      acc += as[c] * Ws0[c * 64 + d] + sp[c] * Wself0[c * 64 + d];
    sh[tid] = acc;
  } else {
    int tid = (b - NA * 64 / 256) * 256 + threadIdx.x;
    int n = tid >> 5, d = tid & 31;
    float a0 = 0, a1 = 0, a2 = 0;
    const float* av = a_v + (size_t)n * 192;
    for (int c = 0; c < 64; ++c) {
      float w = Wv0[c * 32 + d];
      a0 += av[c * 3] * w; a1 += av[c * 3 + 1] * w; a2 += av[c * 3 + 2] * w;
    }
    float* o = vh + (size_t)n * 128 + d * 4;  // padded [n][32][4]
    o[0] = a0; o[1] = a1; o[2] = a2;
  }
}

// ---------------- layer aggregation (wave per node) ----------------
__global__ __launch_bounds__(256, 8) void k_agg_layer(
    const float* __restrict__ cnoise, const float* __restrict__ nsw,
    const int* __restrict__ offsets, const float* __restrict__ rec8,
    const float* __restrict__ TS, const float* __restrict__ TU,
    const float* __restrict__ sh_in, const float* __restrict__ vh_in,
    float* __restrict__ a_s, float* __restrict__ a_v) {
  int lane = threadIdx.x & 63;
  int n = blockIdx.x * 4 + (threadIdx.x >> 6);
  int vc = lane & 31;
  bool low = lane < 32;
  float cn = cnoise[0];
  float scale_s = 1.f + cn * nsw[lane];
  float scale_v = 1.f + cn * nsw[64 + vc];

  float ms = 0;                    // sum w_ss*sh        (scale_s folded at store)
  float av0 = 0, av1 = 0, av2 = 0; // sum w_sv*sh*Y      (scale_s folded)
  float ms2 = 0;                   // low: sum w_vs*(v.Y) (scale_v folded)
  float b0 = 0, b1 = 0, b2 = 0;    // low: w_vv*v ; high: w_vx*cross(v,Y) (scale_v folded)
  int beg = __builtin_amdgcn_readfirstlane(offsets[n]);
  int end = __builtin_amdgcn_readfirstlane(offsets[n + 1]);
  if (beg < end) {
    const float* rp = rec8 + (size_t)beg * 8;
    float4 rA = *(const float4*)rp;
    float2 rB = *(const float2*)(rp + 4);
    for (int idx = beg; idx < end; ++idx) {
      int src = __float_as_int(rA.x);
      float frac = rB.x;
      int qoff = __float_as_int(rB.y);
      float y0 = rA.y, y1 = rA.z, y2 = rA.w;
      // gathers for current edge
      float4 s4 = *(const float4*)(TS + qoff + (lane << 2));
      float4 u4 = *(const float4*)(TU + qoff + (lane << 2));
      float ss = sh_in[((size_t)src << 6) + lane];
      nfloat4 v4 = ((const nfloat4*)(vh_in + ((size_t)src << 7)))[vc];
      // prefetch next record
      int nidx = (idx + 1 < end) ? idx + 1 : idx;
      const float* np = rec8 + (size_t)nidx * 8;
      float4 nA = *(const float4*)np;
      float2 nB = *(const float2*)(np + 4);
      // compute
      float wS  = fmaf(frac, s4.y, s4.x);
      float wSV = fmaf(frac, s4.w, s4.z);
      float wA  = fmaf(frac, u4.y, u4.x);
      float wB  = fmaf(frac, u4.w, u4.z);
      float v0 = v4.x, v1 = v4.y, v2 = v4.z;
      ms += wS * ss;
      float t = wSV * ss;
      av0 += t * y0; av1 += t * y1; av2 += t * y2;
      float vdot = v0 * y0 + v1 * y1 + v2 * y2;
      ms2 += wA * vdot;  // garbage on high lanes, never written
      float cx = v1 * y2 - v2 * y1;
      float cy = v2 * y0 - v0 * y2;
      float cz = v0 * y1 - v1 * y0;
      float m0 = low ? v0 : cx;
      float m1 = low ? v1 : cy;
      float m2 = low ? v2 : cz;
      float wM = low ? wB : wA;
      b0 += wM * m0; b1 += wM * m1; b2 += wM * m2;
      rA = nA; rB = nB;
    }
  }
  float fs = scale_s * INV_NORM;
  float fv = scale_v * INV_NORM;
  a_s[n * 96 + lane] = ms * fs;
  float* avn = a_v + (size_t)n * 384;
  avn[lane * 3] = av0 * fs; avn[lane * 3 + 1] = av1 * fs; avn[lane * 3 + 2] = av2 * fs;
  if (low) {
    a_s[n * 96 + 64 + vc] = ms2 * fv;
    avn[(64 + vc) * 3] = b0 * fv;
    avn[(64 + vc) * 3 + 1] = b1 * fv;
    avn[(64 + vc) * 3 + 2] = b2 * fv;
  } else {
    avn[(96 + vc) * 3] = b0 * fv;
    avn[(96 + vc) * 3 + 1] = b1 * fv;
    avn[(96 + vc) * 3 + 2] = b2 * fv;
  }
}

// ---------------- mixing / self / skip (merged s + v) ----------------
__global__ void k_mix(const float* __restrict__ a_s, const float* __restrict__ sh_in,
                      const float* __restrict__ Wmix_s, const float* __restrict__ Wself_s,
                      const float* __restrict__ a_v, const float* __restrict__ vh_in,
                      const float* __restrict__ Wmix_v, const float* __restrict__ Wself_v,
                      const float* __restrict__ nsw, const float* __restrict__ skw,
                      const float* __restrict__ skb, const float* __restrict__ cnoise,
                      float* __restrict__ sh_out, float* __restrict__ vh_out) {
  int b = blockIdx.x;
  float cn = cnoise[0];
  if (b < NA * 64 / 256) {
    int tid = b * 256 + threadIdx.x;
    int n = tid >> 6, d = tid & 63;
    float acc = 0;
    const float* as = a_s + n * 96;
    for (int cc = 0; cc < 96; ++cc) acc += as[cc] * Wmix_s[cc * 64 + d];
    const float* sp = sh_in + n * 64;
    for (int cc = 0; cc < 64; ++cc) acc += sp[cc] * (1.f + cn * nsw[cc]) * Wself_s[cc * 64 + d];
    float g1 = sigmoidf_(skb[d] + cn * skw[d]);
    float g2 = sigmoidf_(skb[64 + d] + cn * skw[64 + d]);
    sh_out[tid] = g1 * sh_in[tid] + g2 * acc;
  } else {
    int tid = (b - NA * 64 / 256) * 256 + threadIdx.x;
    int n = tid >> 5, d = tid & 31;
    float a0 = 0, a1 = 0, a2 = 0;
    const float* av = a_v + (size_t)n * 384;
    for (int cc = 0; cc < 128; ++cc) {
      float w = Wmix_v[cc * 32 + d];
      a0 += av[cc * 3] * w; a1 += av[cc * 3 + 1] * w; a2 += av[cc * 3 + 2] * w;
    }
    const float* vp = vh_in + (size_t)n * 128;
    for (int cc = 0; cc < 32; ++cc) {
      float w = Wself_v[cc * 32 + d] * (1.f + cn * nsw[64 + cc]);
      a0 += vp[cc * 4] * w; a1 += vp[cc * 4 + 1] * w; a2 += vp[cc * 4 + 2] * w;
    }
    float g3 = sigmoidf_(skb[128 + d] + cn * skw[128 + d]);
    float g4 = sigmoidf_(skb[160 + d] + cn * skw[160 + d]);
    float* o = vh_out + (size_t)n * 128 + d * 4;
    const float* vi = vh_in + (size_t)n * 128 + d * 4;
    o[0] = g3 * vi[0] + g4 * a0;
    o[1] = g3 * vi[1] + g4 * a1;
    o[2] = g3 * vi[2] + g4 * a2;
  }
}

// ---------------- output ----------------
__global__ void k_out(const float* __restrict__ vh, const float* __restrict__ w_out,
                      const float* __restrict__ gain, float* __restrict__ out) {
  int tid = blockIdx.x * 256 + threadIdx.x;  // < NA*3
  int n = tid / 3, i = tid - n * 3;
  float acc = 0;
  for (int c = 0; c < 32; ++c) acc += vh[(size_t)n * 128 + c * 4 + i] * w_out[c];
  out[tid] = acc * gain[0];
}

extern "C" void kernel_launch(void* const* d_in, const int* in_sizes, int n_in,
                              void* d_out, int out_size, void* d_ws, size_t ws_size,
                              hipStream_t stream) {
  (void)in_sizes; (void)n_in; (void)out_size; (void)ws_size;
  const float* pos     = (const float*)d_in[0];
  const float* cn      = (const float*)d_in[1];
  const int*   types   = (const int*)d_in[2];
  const int*   rad     = (const int*)d_in[3];
  const int*   bon     = (const int*)d_in[4];
  const float* atom_tab= (const float*)d_in[5];
  const float* bond_tab= (const float*)d_in[6];
  const float* ns0_w   = (const float*)d_in[7];
  const float* We0     = (const float*)d_in[8];
  const float* We1     = (const float*)d_in[9];
  const float* Wself0  = (const float*)d_in[10];
  const float* Ws0     = (const float*)d_in[11];
  const float* Wv0     = (const float*)d_in[12];
  const float* ns_w    = (const float*)d_in[13];
  const float* We_ss   = (const float*)d_in[14];
  const float* We_vs   = (const float*)d_in[15];
  const float* We_sv   = (const float*)d_in[16];
  const float* We_vv   = (const float*)d_in[17];
  const float* We_vx   = (const float*)d_in[18];
  const float* Wmix_s  = (const float*)d_in[19];
  const float* Wmix_v  = (const float*)d_in[20];
  const float* Wself_s = (const float*)d_in[21];
  const float* Wself_v = (const float*)d_in[22];
  const float* skip_w  = (const float*)d_in[23];
  const float* skip_b  = (const float*)d_in[24];
  const float* w_out   = (const float*)d_in[25];
  const float* gain    = (const float*)d_in[26];

  char* ws = (char*)d_ws;
  size_t o = 0;
  auto alloc = [&](size_t bytes) -> void* {
    void* p = ws + o;
    o += (bytes + 255) & ~(size_t)255;
    return p;
  };
  float* s_feat = (float*)alloc((size_t)NA * 64 * 4);
  float* a_s    = (float*)alloc((size_t)NA * 96 * 4);
  float* a_v    = (float*)alloc((size_t)NA * 384 * 4);
  float* sh0    = (float*)alloc((size_t)NA * 64 * 4);
  float* sh1    = (float*)alloc((size_t)NA * 64 * 4);
  float* vh0    = (float*)alloc((size_t)NA * 128 * 4);  // padded [n][32][4]
  float* vh1    = (float*)alloc((size_t)NA * 128 * 4);
  int* count    = (int*)alloc((size_t)NA * 4);
  int* offsets  = (int*)alloc((size_t)(NA + 1) * 4);
  int* sorted   = (int*)alloc((size_t)ET * 4);
  float* rec8   = (float*)alloc((size_t)ET * 32);
  float* tabs   = (float*)alloc((size_t)5 * TBL_ELEMS * 4);
  float* shb[2] = {sh0, sh1};
  float* vhb[2] = {vh0, vh1};

  // CSR build + tables
  k_zero<<<NA / 256, 256, 0, stream>>>(count);
  k_hist<<<ET / 256, 256, 0, stream>>>(rad, bon, count);
  k_scan<<<1, 256, 0, stream>>>(count, offsets);
  k_fill<<<ET / 256, 256, 0, stream>>>(rad, bon, count, sorted);
  k_edge_pre<<<ET / 256, 256, 0, stream>>>(pos, rad, bon, sorted, rec8);
  k_build<<<dim3(BINS, 5, 2), 64, 0, stream>>>(We0, We1, We_ss, We_vs, We_sv, We_vv, We_vx,
                                               bond_tab, tabs);

  k_embed<<<NA * 64 / 256, 256, 0, stream>>>(atom_tab, types, ns0_w, cn, s_feat);
  k_agg0<<<NA / 4, 256, 0, stream>>>(offsets, rec8, tabs, s_feat, a_s, a_v);
  k_init<<<NA * 64 / 256 + NA * 32 / 256, 256, 0, stream>>>(
      a_s, s_feat, Ws0, Wself0, a_v, Wv0, shb[0], vhb[0]);

  for (int l = 0; l < 2; ++l) {
    int bin = l & 1, bout = 1 - bin;
    const float* TS = tabs + (size_t)(1 + 2 * l) * TBL_ELEMS;
    const float* TU = tabs + (size_t)(2 + 2 * l) * TBL_ELEMS;
    k_agg_layer<<<NA / 4, 256, 0, stream>>>(
        cn, ns_w + l * 96, offsets, rec8, TS, TU, shb[bin], vhb[bin], a_s, a_v);
    k_mix<<<NA * 64 / 256 + NA * 32 / 256, 256, 0, stream>>>(
        a_s, shb[bin], Wmix_s + l * 96 * 64, Wself_s + l * 64 * 64,
        a_v, vhb[bin], Wmix_v + l * 128 * 32, Wself_v + l * 32 * 32,
        ns_w + l * 96, skip_w + l * 192, skip_b + l * 192, cn, shb[bout], vhb[bout]);
  }
  k_out<<<NA * 3 / 256, 256, 0, stream>>>(vhb[0], w_out, gain, (float*)d_out);
}

// Round 8
// 598.903 us; speedup vs baseline: 1.0003x; 1.0003x over previous
//
#include <hip/hip_runtime.h>
#include <math.h>

#define NA 16384
#define ER 524288
#define EB 32768
#define ET 557056
#define INV_NORM 0.17149858514250882f   // 1/sqrt((ER+EB)/NA) = 1/sqrt(34)
#define SQRT3 1.7320508075688772f
#define RB_STEP (1.5f/9.0f)
#define BINS 512
#define DMAX 2.5f
#define INV_H ((float)BINS / DMAX)
#define TBL_ELEMS (2 * BINS * 256)   // one table: [2][BINS][64][4] floats

__device__ __forceinline__ float sigmoidf_(float x) { return 1.f / (1.f + __expf(-x)); }

__device__ __forceinline__ int edge_dst(int e, const int* __restrict__ rad, const int* __restrict__ bon) {
  return (e < ER) ? rad[ER + e] : bon[EB + (e - ER)];
}

// ---------------- CSR build ----------------
__global__ void k_zero(int* __restrict__ count) {
  count[blockIdx.x * 256 + threadIdx.x] = 0;
}

__global__ void k_hist(const int* __restrict__ rad, const int* __restrict__ bon, int* __restrict__ count) {
  int e = blockIdx.x * 256 + threadIdx.x;
  atomicAdd(&count[edge_dst(e, rad, bon)], 1);
}

__global__ void k_scan(int* __restrict__ count, int* __restrict__ offsets) {
  __shared__ int part[256];
  int t = threadIdx.x;
  int base = t * 64;
  int s = 0;
  for (int j = 0; j < 64; ++j) s += count[base + j];
  part[t] = s;
  __syncthreads();
  for (int off = 1; off < 256; off <<= 1) {
    int v = (t >= off) ? part[t - off] : 0;
    __syncthreads();
    part[t] += v;
    __syncthreads();
  }
  int run = part[t] - s;  // exclusive prefix
  for (int j = 0; j < 64; ++j) {
    int c = count[base + j];
    offsets[base + j] = run;
    count[base + j] = run;  // becomes cursor for k_fill
    run += c;
  }
  if (t == 255) offsets[NA] = run;
}

__global__ void k_fill(const int* __restrict__ rad, const int* __restrict__ bon,
                       int* __restrict__ cursor, int* __restrict__ sorted) {
  int e = blockIdx.x * 256 + threadIdx.x;
  int d = edge_dst(e, rad, bon);
  int slot = atomicAdd(&cursor[d], 1);
  sorted[slot] = e;
}

// ---------------- per-edge record precompute ----------------
// record[idx] (32B): {src, Y0, Y1, Y2, frac, qoff(elem offset into a table), pad, pad}
__global__ void k_edge_pre(const float* __restrict__ pos,
                           const int* __restrict__ rad, const int* __restrict__ bon,
                           const int* __restrict__ sorted, float* __restrict__ rec8) {
  int idx = blockIdx.x * 256 + threadIdx.x;
  int e = sorted[idx];
  int src, dst, v;
  if (e < ER) { src = rad[e]; dst = rad[ER + e]; v = 0; }
  else        { src = bon[e - ER]; dst = bon[EB + e - ER]; v = 1; }
  float dx = pos[src * 3] - pos[dst * 3];
  float dy = pos[src * 3 + 1] - pos[dst * 3 + 1];
  float dz = pos[src * 3 + 2] - pos[dst * 3 + 2];
  float dist = sqrtf(dx * dx + dy * dy + dz * dz + 1e-12f);
  float inv = 1.f / dist;
  float fq = fminf(dist * INV_H, BINS - 1.001f);
  int q = (int)fq;
  float frac = fq - (float)q;
  int qoff = (v * BINS + q) << 8;   // 256 floats per row
  float* rp = rec8 + (size_t)idx * 8;
  *(float4*)rp = make_float4(__int_as_float(src), SQRT3 * dx * inv, SQRT3 * dy * inv, SQRT3 * dz * inv);
  rp[4] = frac;
  rp[5] = __int_as_float(qoff);
}

// ---------------- radial-weight tables with bond base folded ----------------
__global__ void k_build(const float* __restrict__ We0, const float* __restrict__ We1,
                        const float* __restrict__ We_ss, const float* __restrict__ We_vs,
                        const float* __restrict__ We_sv, const float* __restrict__ We_vv,
                        const float* __restrict__ We_vx, const float* __restrict__ bond_tab,
                        float* __restrict__ tabs) {
  int q = blockIdx.x, t = blockIdx.y, v = blockIdx.z, c = threadIdx.x;
  float d0 = q * (DMAX / BINS), d1 = (q + 1) * (DMAX / BINS);
  float rb0[8], rb1[8];
#pragma unroll
  for (int k = 0; k < 8; ++k) {
    float f0 = (d0 - (k + 1) * RB_STEP) * (1.f / RB_STEP);
    float f1 = (d1 - (k + 1) * RB_STEP) * (1.f / RB_STEP);
    rb0[k] = 1.12f * __expf(-f0 * f0);
    rb1[k] = 1.12f * __expf(-f1 * f1);
  }
  const float* A;
  const float* B;
  int stride, coff;
  bool hasB = true;
  if (t == 0) { A = We0; B = We1; stride = 64; coff = c; }
  else if (t == 1 || t == 3) {
    int l = (t == 3);
    A = We_ss + l * 1024; B = We_sv + l * 1024; stride = 64; coff = c;
  } else {
    int l = (t == 4);
    stride = 32; coff = c & 31;
    if (c < 32) { A = We_vs + l * 512; B = We_vv + l * 512; }
    else        { A = We_vx + l * 512; B = nullptr; hasB = false; }
  }
  float ba = 0, bb = 0, a0 = 0, a1 = 0, b0 = 0, b1 = 0;
#pragma unroll
  for (int k = 0; k < 8; ++k) {
    float bt = bond_tab[v * 8 + k];
    float av_lo = A[k * stride + coff], av_hi = A[(8 + k) * stride + coff];
    ba += bt * av_lo;
    a0 += rb0[k] * av_hi; a1 += rb1[k] * av_hi;
    if (hasB) {
      float bv_lo = B[k * stride + coff], bv_hi = B[(8 + k) * stride + coff];
      bb += bt * bv_lo;
      b0 += rb0[k] * bv_hi; b1 += rb1[k] * bv_hi;
    }
  }
  float* o = tabs + (size_t)t * TBL_ELEMS + (((size_t)v * BINS + q) << 8) + c * 4;
  o[0] = ba + a0; o[1] = a1 - a0; o[2] = bb + b0; o[3] = b1 - b0;
}

// ---------------- embedding ----------------
__global__ void k_embed(const float* __restrict__ atom_tab, const int* __restrict__ types,
                        const float* __restrict__ ns0_w, const float* __restrict__ cnoise,
                        float* __restrict__ s_feat) {
  int tid = blockIdx.x * 256 + threadIdx.x;
  int n = tid >> 6, c = tid & 63;
  float cn = cnoise[0];
  s_feat[tid] = atom_tab[types[n] * 64 + c] * (1.f + cn * ns0_w[c]);
}

// ---------------- initial aggregation (wave per node, lane = channel) ----------------
// a_v0 layout: [n][64][4] (pad)
__global__ __launch_bounds__(256, 6) void k_agg0(
    const int* __restrict__ offsets, const float* __restrict__ rec8,
    const float* __restrict__ T0, const float* __restrict__ s_feat,
    float* __restrict__ a_s, float* __restrict__ a_v) {
  int lane = threadIdx.x & 63;
  int n = blockIdx.x * 4 + (threadIdx.x >> 6);
  float acc = 0, a0 = 0, a1 = 0, a2 = 0;
  int beg = __builtin_amdgcn_readfirstlane(offsets[n]);
  int end = __builtin_amdgcn_readfirstlane(offsets[n + 1]);
  if (beg < end) {
    const float* rp0 = rec8 + (size_t)beg * 8;
    float4 rA = *(const float4*)rp0;
    float2 rB = *(const float2*)(rp0 + 4);
    int i1 = beg + (beg + 1 < end ? 1 : 0);
    const float* rp1 = rec8 + (size_t)i1 * 8;
    float4 nA = *(const float4*)rp1;
    float2 nB = *(const float2*)(rp1 + 4);
    // gathers for edge 0
    float4 t4 = *(const float4*)(T0 + __float_as_int(rB.y) + (lane << 2));
    float sv = s_feat[((size_t)__float_as_int(rA.x) << 6) + lane];
#pragma unroll 2
    for (int idx = beg; idx < end; ++idx) {
      // prefetch gathers for idx+1 (from nA/nB), rec for idx+2
      float4 pt4 = *(const float4*)(T0 + __float_as_int(nB.y) + (lane << 2));
      float psv = s_feat[((size_t)__float_as_int(nA.x) << 6) + lane];
      int i2 = (idx + 2 < end) ? idx + 2 : end - 1;
      const float* rp2 = rec8 + (size_t)i2 * 8;
      float4 fA = *(const float4*)rp2;
      float2 fB = *(const float2*)(rp2 + 4);
      // compute current
      float frac = rB.x;
      float w0 = fmaf(frac, t4.y, t4.x);
      float w1 = fmaf(frac, t4.w, t4.z);
      acc += w0 * sv;
      float t = w1 * sv;
      a0 += t * rA.y; a1 += t * rA.z; a2 += t * rA.w;
      // rotate
      rA = nA; rB = nB; nA = fA; nB = fB; t4 = pt4; sv = psv;
    }
  }
  a_s[n * 64 + lane] = acc * INV_NORM;
  *(float4*)(a_v + ((size_t)n << 8) + (lane << 2)) =
      make_float4(a0 * INV_NORM, a1 * INV_NORM, a2 * INV_NORM, 0.f);
}

// ---------------- initial projections (merged sh + vh) ----------------
__global__ __launch_bounds__(256, 4) void k_init(
    const float* __restrict__ a_s, const float* __restrict__ s_feat,
    const float* __restrict__ Ws0, const float* __restrict__ Wself0,
    const float* __restrict__ a_v, const float* __restrict__ Wv0,
    float* __restrict__ sh, float* __restrict__ vh) {
  int b = blockIdx.x;
  if (b < NA * 64 / 256) {
    int tid = b * 256 + threadIdx.x;
    int n = tid >> 6, d = tid & 63;
    const float4* as4 = (const float4*)(a_s + n * 64);
    const float4* sp4 = (const float4*)(s_feat + n * 64);
    float acc0 = 0, acc1 = 0, acc2 = 0, acc3 = 0;
#pragma unroll
    for (int c4 = 0; c4 < 16; ++c4) {
      float4 a4 = as4[c4];
      float4 s4 = sp4[c4];
      int c = c4 * 4;
      acc0 += a4.x * Ws0[(c + 0) * 64 + d] + s4.x * Wself0[(c + 0) * 64 + d];
      acc1 += a4.y * Ws0[(c + 1) * 64 + d] + s4.y * Wself0[(c + 1) * 64 + d];
      acc2 += a4.z * Ws0[(c + 2) * 64 + d] + s4.z * Wself0[(c + 2) * 64 + d];
      acc3 += a4.w * Ws0[(c + 3) * 64 + d] + s4.w * Wself0[(c + 3) * 64 + d];
    }
    sh[tid] = (acc0 + acc1) + (acc2 + acc3);
  } else {
    int tid = (b - NA * 64 / 256) * 256 + threadIdx.x;
    int n = tid >> 5, d = tid & 31;
    float a0 = 0, a1 = 0, a2 = 0;
    const float4* av4 = (const float4*)(a_v + ((size_t)n << 8));
#pragma unroll 8
    for (int c = 0; c < 64; ++c) {
      float4 a = av4[c];
      float w = Wv0[c * 32 + d];
      a0 += a.x * w; a1 += a.y * w; a2 += a.z * w;
    }
    *(float4*)(vh + ((size_t)n << 7) + (d << 2)) = make_float4(a0, a1, a2, 0.f);
  }
}

// ---------------- layer aggregation (wave per node) ----------------
// a_v layout: [n][128][4] (pad)
__global__ __launch_bounds__(256, 6) void k_agg_layer(
    const float* __restrict__ cnoise, const float* __restrict__ nsw,
    const int* __restrict__ offsets, const float* __restrict__ rec8,
    const float* __restrict__ TS, const float* __restrict__ TU,
    const float* __restrict__ sh_in, const float* __restrict__ vh_in,
    float* __restrict__ a_s, float* __restrict__ a_v) {
  int lane = threadIdx.x & 63;
  int n = blockIdx.x * 4 + (threadIdx.x >> 6);
  int vc = lane & 31;
  bool low = lane < 32;
  float cn = cnoise[0];
  float scale_s = 1.f + cn * nsw[lane];
  float scale_v = 1.f + cn * nsw[64 + vc];

  float ms = 0;
  float av0 = 0, av1 = 0, av2 = 0;
  float ms2 = 0;
  float b0 = 0, b1 = 0, b2 = 0;
  int beg = __builtin_amdgcn_readfirstlane(offsets[n]);
  int end = __builtin_amdgcn_readfirstlane(offsets[n + 1]);
  if (beg < end) {
    const float* rp0 = rec8 + (size_t)beg * 8;
    float4 rA = *(const float4*)rp0;
    float2 rB = *(const float2*)(rp0 + 4);
    int i1 = beg + (beg + 1 < end ? 1 : 0);
    const float* rp1 = rec8 + (size_t)i1 * 8;
    float4 nA = *(const float4*)rp1;
    float2 nB = *(const float2*)(rp1 + 4);
    // gathers for edge 0
    int src0 = __float_as_int(rA.x);
    int qo0 = __float_as_int(rB.y);
    float4 s4 = *(const float4*)(TS + qo0 + (lane << 2));
    float4 u4 = *(const float4*)(TU + qo0 + (lane << 2));
    float ss = sh_in[((size_t)src0 << 6) + lane];
    float4 v4 = *(const float4*)(vh_in + ((size_t)src0 << 7) + (vc << 2));
#pragma unroll 2
    for (int idx = beg; idx < end; ++idx) {
      // prefetch gathers for idx+1 and rec for idx+2
      int nsrc = __float_as_int(nA.x);
      int nqo = __float_as_int(nB.y);
      float4 ps4 = *(const float4*)(TS + nqo + (lane << 2));
      float4 pu4 = *(const float4*)(TU + nqo + (lane << 2));
      float pss = sh_in[((size_t)nsrc << 6) + lane];
      float4 pv4 = *(const float4*)(vh_in + ((size_t)nsrc << 7) + (vc << 2));
      int i2 = (idx + 2 < end) ? idx + 2 : end - 1;
      const float* rp2 = rec8 + (size_t)i2 * 8;
      float4 fA = *(const float4*)rp2;
      float2 fB = *(const float2*)(rp2 + 4);
      // compute current
      float frac = rB.x;
      float y0 = rA.y, y1 = rA.z, y2 = rA.w;
      float wS  = fmaf(frac, s4.y, s4.x);
      float wSV = fmaf(frac, s4.w, s4.z);
      float wA  = fmaf(frac, u4.y, u4.x);
      float wB  = fmaf(frac, u4.w, u4.z);
      float v0 = v4.x, v1 = v4.y, v2 = v4.z;
      ms += wS * ss;
      float t = wSV * ss;
      av0 += t * y0; av1 += t * y1; av2 += t * y2;
      float vdot = v0 * y0 + v1 * y1 + v2 * y2;
      ms2 += wA * vdot;  // garbage on high lanes, never written
      float cx = v1 * y2 - v2 * y1;
      float cy = v2 * y0 - v0 * y2;
      float cz = v0 * y1 - v1 * y0;
      float m0 = low ? v0 : cx;
      float m1 = low ? v1 : cy;
      float m2 = low ? v2 : cz;
      float wM = low ? wB : wA;
      b0 += wM * m0; b1 += wM * m1; b2 += wM * m2;
      // rotate
      rA = nA; rB = nB; nA = fA; nB = fB;
      s4 = ps4; u4 = pu4; ss = pss; v4 = pv4;
    }
  }
  float fs = scale_s * INV_NORM;
  float fv = scale_v * INV_NORM;
  a_s[n * 96 + lane] = ms * fs;
  float* avn = a_v + ((size_t)n << 9);
  *(float4*)(avn + (lane << 2)) = make_float4(av0 * fs, av1 * fs, av2 * fs, 0.f);
  if (low) {
    a_s[n * 96 + 64 + vc] = ms2 * fv;
    *(float4*)(avn + ((64 + vc) << 2)) = make_float4(b0 * fv, b1 * fv, b2 * fv, 0.f);
  } else {
    *(float4*)(avn + ((96 + vc) << 2)) = make_float4(b0 * fv, b1 * fv, b2 * fv, 0.f);
  }
}

// ---------------- mixing / self / skip (merged s + v) ----------------
__global__ __launch_bounds__(256, 4) void k_mix(
    const float* __restrict__ a_s, const float* __restrict__ sh_in,
    const float* __restrict__ Wmix_s, const float* __restrict__ Wself_s,
    const float* __restrict__ a_v, const float* __restrict__ vh_in,
    const float* __restrict__ Wmix_v, const float* __restrict__ Wself_v,
    const float* __restrict__ nsw, const float* __restrict__ skw,
    const float* __restrict__ skb, const float* __restrict__ cnoise,
    float* __restrict__ sh_out, float* __restrict__ vh_out) {
  int b = blockIdx.x;
  float cn = cnoise[0];
  if (b < NA * 64 / 256) {
    int tid = b * 256 + threadIdx.x;
    int n = tid >> 6, d = tid & 63;
    const float4* as4 = (const float4*)(a_s + n * 96);
    float acc0 = 0, acc1 = 0, acc2 = 0, acc3 = 0;
#pragma unroll
    for (int c4 = 0; c4 < 24; ++c4) {
      float4 a4 = as4[c4];
      int c = c4 * 4;
      acc0 += a4.x * Wmix_s[(c + 0) * 64 + d];
      acc1 += a4.y * Wmix_s[(c + 1) * 64 + d];
      acc2 += a4.z * Wmix_s[(c + 2) * 64 + d];
      acc3 += a4.w * Wmix_s[(c + 3) * 64 + d];
    }
    const float4* sp4 = (const float4*)(sh_in + n * 64);
    const float4* nsw4 = (const float4*)nsw;
#pragma unroll
    for (int c4 = 0; c4 < 16; ++c4) {
      float4 s4 = sp4[c4];
      float4 w4 = nsw4[c4];
      int c = c4 * 4;
      acc0 += s4.x * (1.f + cn * w4.x) * Wself_s[(c + 0) * 64 + d];
      acc1 += s4.y * (1.f + cn * w4.y) * Wself_s[(c + 1) * 64 + d];
      acc2 += s4.z * (1.f + cn * w4.z) * Wself_s[(c + 2) * 64 + d];
      acc3 += s4.w * (1.f + cn * w4.w) * Wself_s[(c + 3) * 64 + d];
    }
    float acc = (acc0 + acc1) + (acc2 + acc3);
    float g1 = sigmoidf_(skb[d] + cn * skw[d]);
    float g2 = sigmoidf_(skb[64 + d] + cn * skw[64 + d]);
    sh_out[tid] = g1 * sh_in[tid] + g2 * acc;
  } else {
    int tid = (b - NA * 64 / 256) * 256 + threadIdx.x;
    int n = tid >> 5, d = tid & 31;
    float a0 = 0, a1 = 0, a2 = 0;
    const float4* av4 = (const float4*)(a_v + ((size_t)n << 9));
#pragma unroll 8
    for (int c = 0; c < 128; ++c) {
      float4 a = av4[c];
      float w = Wmix_v[c * 32 + d];
      a0 += a.x * w; a1 += a.y * w; a2 += a.z * w;
    }
    const float4* vp4 = (const float4*)(vh_in + ((size_t)n << 7));
#pragma unroll 8
    for (int c = 0; c < 32; ++c) {
      float4 vv = vp4[c];
      float w = Wself_v[c * 32 + d] * (1.f + cn * nsw[64 + c]);
      a0 += vv.x * w; a1 += vv.y * w; a2 += vv.z * w;
    }
    float g3 = sigmoidf_(skb[128 + d] + cn * skw[128 + d]);
    float g4 = sigmoidf_(skb[160 + d] + cn * skw[160 + d]);
    const float* vi = vh_in + ((size_t)n << 7) + (d << 2);
    *(float4*)(vh_out + ((size_t)n << 7) + (d << 2)) =
        make_float4(g3 * vi[0] + g4 * a0, g3 * vi[1] + g4 * a1, g3 * vi[2] + g4 * a2, 0.f);
  }
}

// ---------------- output ----------------
__global__ void k_out(const float* __restrict__ vh, const float* __restrict__ w_out,
                      const float* __restrict__ gain, float* __restrict__ out) {
  int tid = blockIdx.x * 256 + threadIdx.x;  // < NA*3
  int n = tid / 3, i = tid - n * 3;
  float acc = 0;
  for (int c = 0; c < 32; ++c) acc += vh[((size_t)n << 7) + c * 4 + i] * w_out[c];
  out[tid] = acc * gain[0];
}

extern "C" void kernel_launch(void* const* d_in, const int* in_sizes, int n_in,
                              void* d_out, int out_size, void* d_ws, size_t ws_size,
                              hipStream_t stream) {
  (void)in_sizes; (void)n_in; (void)out_size; (void)ws_size;
  const float* pos     = (const float*)d_in[0];
  const float* cn      = (const float*)d_in[1];
  const int*   types   = (const int*)d_in[2];
  const int*   rad     = (const int*)d_in[3];
  const int*   bon     = (const int*)d_in[4];
  const float* atom_tab= (const float*)d_in[5];
  const float* bond_tab= (const float*)d_in[6];
  const float* ns0_w   = (const float*)d_in[7];
  const float* We0     = (const float*)d_in[8];
  const float* We1     = (const float*)d_in[9];
  const float* Wself0  = (const float*)d_in[10];
  const float* Ws0     = (const float*)d_in[11];
  const float* Wv0     = (const float*)d_in[12];
  const float* ns_w    = (const float*)d_in[13];
  const float* We_ss   = (const float*)d_in[14];
  const float* We_vs   = (const float*)d_in[15];
  const float* We_sv   = (const float*)d_in[16];
  const float* We_vv   = (const float*)d_in[17];
  const float* We_vx   = (const float*)d_in[18];
  const float* Wmix_s  = (const float*)d_in[19];
  const float* Wmix_v  = (const float*)d_in[20];
  const float* Wself_s = (const float*)d_in[21];
  const float* Wself_v = (const float*)d_in[22];
  const float* skip_w  = (const float*)d_in[23];
  const float* skip_b  = (const float*)d_in[24];
  const float* w_out   = (const float*)d_in[25];
  const float* gain    = (const float*)d_in[26];

  char* ws = (char*)d_ws;
  size_t o = 0;
  auto alloc = [&](size_t bytes) -> void* {
    void* p = ws + o;
    o += (bytes + 255) & ~(size_t)255;
    return p;
  };
  float* s_feat = (float*)alloc((size_t)NA * 64 * 4);
  float* a_s    = (float*)alloc((size_t)NA * 96 * 4);
  float* a_v    = (float*)alloc((size_t)NA * 512 * 4);  // padded [n][128][4]
  float* sh0    = (float*)alloc((size_t)NA * 64 * 4);
  float* sh1    = (float*)alloc((size_t)NA * 64 * 4);
  float* vh0    = (float*)alloc((size_t)NA * 128 * 4);  // padded [n][32][4]
  float* vh1    = (float*)alloc((size_t)NA * 128 * 4);
  int* count    = (int*)alloc((size_t)NA * 4);
  int* offsets  = (int*)alloc((size_t)(NA + 1) * 4);
  int* sorted   = (int*)alloc((size_t)ET * 4);
  float* rec8   = (float*)alloc((size_t)ET * 32);
  float* tabs   = (float*)alloc((size_t)5 * TBL_ELEMS * 4);
  float* shb[2] = {sh0, sh1};
  float* vhb[2] = {vh0, vh1};

  // CSR build + tables
  k_zero<<<NA / 256, 256, 0, stream>>>(count);
  k_hist<<<ET / 256, 256, 0, stream>>>(rad, bon, count);
  k_scan<<<1, 256, 0, stream>>>(count, offsets);
  k_fill<<<ET / 256, 256, 0, stream>>>(rad, bon, count, sorted);
  k_edge_pre<<<ET / 256, 256, 0, stream>>>(pos, rad, bon, sorted, rec8);
  k_build<<<dim3(BINS, 5, 2), 64, 0, stream>>>(We0, We1, We_ss, We_vs, We_sv, We_vv, We_vx,
                                               bond_tab, tabs);

  k_embed<<<NA * 64 / 256, 256, 0, stream>>>(atom_tab, types, ns0_w, cn, s_feat);
  k_agg0<<<NA / 4, 256, 0, stream>>>(offsets, rec8, tabs, s_feat, a_s, a_v);
  k_init<<<NA * 64 / 256 + NA * 32 / 256, 256, 0, stream>>>(
      a_s, s_feat, Ws0, Wself0, a_v, Wv0, shb[0], vhb[0]);

  for (int l = 0; l < 2; ++l) {
    int bin = l & 1, bout = 1 - bin;
    const float* TS = tabs + (size_t)(1 + 2 * l) * TBL_ELEMS;
    const float* TU = tabs + (size_t)(2 + 2 * l) * TBL_ELEMS;
    k_agg_layer<<<NA / 4, 256, 0, stream>>>(
        cn, ns_w + l * 96, offsets, rec8, TS, TU, shb[bin], vhb[bin], a_s, a_v);
    k_mix<<<NA * 64 / 256 + NA * 32 / 256, 256, 0, stream>>>(
        a_s, shb[bin], Wmix_s + l * 96 * 64, Wself_s + l * 64 * 64,
        a_v, vhb[bin], Wmix_v + l * 128 * 32, Wself_v + l * 32 * 32,
        ns_w + l * 96, skip_w + l * 192, skip_b + l * 192, cn, shb[bout], vhb[bout]);
  }
  k_out<<<NA * 3 / 256, 256, 0, stream>>>(vhb[0], w_out, gain, (float*)d_out);
}